// Round 3
// baseline (551.623 us; speedup 1.0000x reference)
//
#include <hip/hip_runtime.h>
#include <hip/hip_bf16.h>

// GraphSAGE R8:
//  (a) Gather quad-coalescing: lane (row,seg) owns col chunks [32t+8seg,+8)
//      so each gather instruction's quad reads ONE fully-used 64B line
//      (was: 4 lines at 25% use -> 4x TA line-touch amplification).
//  (b) fused_layer LDS 34816 -> 32768 via XOR swizzle (soff ^ ((row&7)<<3))
//      instead of LDAF=136 padding -> exactly 5 blocks/CU (was 4),
//      launch_bounds(256,5). ds_read_b128 stays 2-way (free) under swizzle.
//  Keeps R7: fragment-swizzled B in global (coalesced L2 frags, no B LDS),
//  software-pipelined gemm1, barrier-free fused k-loop.

constexpr int N_NODES = 100000;
constexpr int FANOUT  = 16;

typedef __attribute__((ext_vector_type(8))) short short8;
typedef __attribute__((ext_vector_type(4))) float f32x4;

__device__ inline unsigned short bf16_rne(float f) {
    unsigned u = __float_as_uint(f);
    return (unsigned short)((u + 0x7fffu + ((u >> 16) & 1u)) >> 16);
}
__device__ inline float bf16_tof(unsigned short s) {
    return __uint_as_float(((unsigned)s) << 16);
}

// ---- weights -> hi/lo bf16, FRAGMENT-SWIZZLED layout ----
// off(c,k) = ((tk*(C/16)+tc)*64 + qk*16 + mlc)*8 + e
//   tc=c>>4, mlc=c&15, tk=k>>5, qk=(k>>3)&3, e=k&7
__global__ __launch_bounds__(256)
void prep_Bsw(const float* __restrict__ W, unsigned short* __restrict__ Bhi,
              unsigned short* __restrict__ Blo, int D_IN, int D_OUT)
{
    int i = blockIdx.x * 256 + threadIdx.x;
    int total = 2 * D_OUT * D_IN;
    if (i >= total) return;
    int K = D_IN, C = 2 * D_OUT;
    int c = i / K, k = i % K;
    float v = (c < D_OUT) ? W[(size_t)c * (2 * K) + k]
                          : W[(size_t)(c - D_OUT) * (2 * K) + K + k];
    int tc = c >> 4, mlc = c & 15;
    int tk = k >> 5, qk = (k >> 3) & 3, e = k & 7;
    size_t off = ((size_t)(tk * (C / 16) + tc) * 64 + qk * 16 + mlc) * 8 + e;
    unsigned short hi = bf16_rne(v);
    Bhi[off] = hi;
    Blo[off] = bf16_rne(v - bf16_tof(hi));
}

// ---- gemm1: dense, K=256, C=256. block = 64 nodes, wave tile 64x64. ----
// A: software-pipelined fp32->split-bf16 LDS staging. B: swizzled global (L2).
__global__ __launch_bounds__(256, 3)
void gemm1(const float* __restrict__ hf,
           const unsigned short* __restrict__ Bhi,
           const unsigned short* __restrict__ Blo,
           float* __restrict__ gs, unsigned short* __restrict__ gn, int N)
{
    constexpr int K = 256, DO = 128, LDA = 40;
    __shared__ unsigned short Ah[64 * LDA], Al[64 * LDA];

    const int tid  = threadIdx.x;
    const int wave = tid >> 6;
    const int lane = tid & 63;
    const int ml   = lane & 15;
    const int quad = lane >> 4;
    const int node0 = blockIdx.x * 64;

    const int srow = tid >> 3;
    const int sc4  = tid & 7;
    int nd0 = node0 + srow;      if (nd0 >= N) nd0 = N - 1;
    int nd1 = node0 + srow + 32; if (nd1 >= N) nd1 = N - 1;
    const float* pA0 = &hf[(size_t)nd0 * K + sc4 * 4];
    const float* pA1 = &hf[(size_t)nd1 * K + sc4 * 4];

    f32x4 acc[4][4];
    #pragma unroll
    for (int mi = 0; mi < 4; ++mi)
        #pragma unroll
        for (int ni = 0; ni < 4; ++ni)
            acc[mi][ni] = (f32x4){0.f, 0.f, 0.f, 0.f};

    float4 pf0 = *(const float4*)&pA0[0];
    float4 pf1 = *(const float4*)&pA1[0];

    for (int k0 = 0; k0 < K; k0 += 32) {
        {
            float v0[4] = {pf0.x, pf0.y, pf0.z, pf0.w};
            float v1[4] = {pf1.x, pf1.y, pf1.z, pf1.w};
            unsigned short h0[4], l0[4], h1[4], l1[4];
            #pragma unroll
            for (int e = 0; e < 4; ++e) {
                h0[e] = bf16_rne(v0[e]); l0[e] = bf16_rne(v0[e] - bf16_tof(h0[e]));
                h1[e] = bf16_rne(v1[e]); l1[e] = bf16_rne(v1[e] - bf16_tof(h1[e]));
            }
            *(uint2*)&Ah[srow * LDA + sc4 * 4]        = *(const uint2*)h0;
            *(uint2*)&Al[srow * LDA + sc4 * 4]        = *(const uint2*)l0;
            *(uint2*)&Ah[(srow + 32) * LDA + sc4 * 4] = *(const uint2*)h1;
            *(uint2*)&Al[(srow + 32) * LDA + sc4 * 4] = *(const uint2*)l1;
        }
        if (k0 + 32 < K) {
            pf0 = *(const float4*)&pA0[k0 + 32];
            pf1 = *(const float4*)&pA1[k0 + 32];
        }
        __syncthreads();

        short8 afh[4], afl[4];
        #pragma unroll
        for (int mi = 0; mi < 4; ++mi) {
            int r = mi * 16 + ml;
            afh[mi] = *(const short8*)&Ah[r * LDA + quad * 8];
            afl[mi] = *(const short8*)&Al[r * LDA + quad * 8];
        }
        const size_t bbase = (size_t)((k0 >> 5) * 16 + wave * 4) * 512 + (size_t)lane * 8;
        #pragma unroll
        for (int ni = 0; ni < 4; ++ni) {
            short8 bh = *(const short8*)&Bhi[bbase + ni * 512];
            short8 bl = *(const short8*)&Blo[bbase + ni * 512];
            #pragma unroll
            for (int mi = 0; mi < 4; ++mi) {
                acc[mi][ni] = __builtin_amdgcn_mfma_f32_16x16x32_bf16(afl[mi], bh, acc[mi][ni], 0, 0, 0);
                acc[mi][ni] = __builtin_amdgcn_mfma_f32_16x16x32_bf16(afh[mi], bl, acc[mi][ni], 0, 0, 0);
                acc[mi][ni] = __builtin_amdgcn_mfma_f32_16x16x32_bf16(afh[mi], bh, acc[mi][ni], 0, 0, 0);
            }
        }
        __syncthreads();
    }

    #pragma unroll
    for (int mi = 0; mi < 4; ++mi)
        #pragma unroll
        for (int r = 0; r < 4; ++r) {
            int node = node0 + mi * 16 + quad * 4 + r;
            if (node >= N) continue;
            #pragma unroll
            for (int ni = 0; ni < 4; ++ni) {
                int c = wave * 64 + ni * 16 + ml;
                float v = acc[mi][ni][r];
                if (c < DO) gs[(size_t)node * DO + c] = v;
                else        gn[(size_t)node * DO + (c - DO)] = bf16_rne(v);
            }
        }
}

// ---- fused layer: quad-coalesced gather + XOR-swizzled A-LDS + MFMA ----
// D_IN=128 fixed. C=256 (DO=128) or C=128 (DO=64). 5 blocks/CU.
template<int C>
__global__ __launch_bounds__(256, 5)
void fused_layer(const float* __restrict__ gs_in,
                 const unsigned short* __restrict__ gn_in,
                 const int* __restrict__ neigh,
                 const unsigned short* __restrict__ Bhi,
                 const unsigned short* __restrict__ Blo,
                 float* __restrict__ gs_out,
                 unsigned short* __restrict__ gn_out, int N)
{
    constexpr int K = 128, DO = C / 2, NI = C / 64;
    __shared__ unsigned short Afh[64 * 128], Afl[64 * 128];   // 32768 B total

    const int tid  = threadIdx.x;
    const int wave = tid >> 6;
    const int lane = tid & 63;
    const int ml   = lane & 15;
    const int quad = lane >> 4;
    const int node0 = blockIdx.x * 64;

    // ---- A-phase: h = relu(gs + mean*gn[nb]); lane (row,seg) owns col
    // chunks [32t+8seg, +8) t=0..3 -> quad instruction = one full 64B line.
    {
        const int row = tid >> 2;
        const int seg = tid & 3;
        int nd = node0 + row; if (nd >= N) nd = N - 1;
        const int4* nb4 = (const int4*)(neigh + (size_t)nd * FANOUT);
        int4 q0 = nb4[0], q1 = nb4[1], q2 = nb4[2], q3 = nb4[3];
        int ids[FANOUT] = {q0.x, q0.y, q0.z, q0.w, q1.x, q1.y, q1.z, q1.w,
                           q2.x, q2.y, q2.z, q2.w, q3.x, q3.y, q3.z, q3.w};
        float acc[32];
        #pragma unroll
        for (int c = 0; c < 32; ++c) acc[c] = 0.f;
        #pragma unroll
        for (int j = 0; j < FANOUT; ++j) {
            const uint4* src = (const uint4*)&gn_in[(size_t)ids[j] * 128];
            #pragma unroll
            for (int t = 0; t < 4; ++t) {
                uint4 q = src[4 * t + seg];
                acc[t*8+0] += __uint_as_float(q.x << 16);
                acc[t*8+1] += __uint_as_float(q.x & 0xffff0000u);
                acc[t*8+2] += __uint_as_float(q.y << 16);
                acc[t*8+3] += __uint_as_float(q.y & 0xffff0000u);
                acc[t*8+4] += __uint_as_float(q.z << 16);
                acc[t*8+5] += __uint_as_float(q.z & 0xffff0000u);
                acc[t*8+6] += __uint_as_float(q.w << 16);
                acc[t*8+7] += __uint_as_float(q.w & 0xffff0000u);
            }
        }
        const float inv = 1.0f / (float)FANOUT;
        const float* gsp = &gs_in[(size_t)nd * 128];
        #pragma unroll
        for (int t = 0; t < 4; ++t) {
            float4 s0 = *(const float4*)&gsp[32 * t + 8 * seg];
            float4 s1 = *(const float4*)&gsp[32 * t + 8 * seg + 4];
            float sv[8] = {s0.x, s0.y, s0.z, s0.w, s1.x, s1.y, s1.z, s1.w};
            alignas(16) unsigned short th[8], tl[8];
            #pragma unroll
            for (int e = 0; e < 8; ++e) {
                float h = fmaxf(fmaf(acc[t*8+e], inv, sv[e]), 0.f);
                unsigned short hi = bf16_rne(h);
                th[e] = hi;
                tl[e] = bf16_rne(h - bf16_tof(hi));
            }
            int soff = (row * 128 + 32 * t + 8 * seg) ^ ((row & 7) << 3);
            *(uint4*)&Afh[soff] = *(const uint4*)th;
            *(uint4*)&Afl[soff] = *(const uint4*)tl;
        }
    }
    __syncthreads();

    f32x4 acc[4][NI];
    #pragma unroll
    for (int mi = 0; mi < 4; ++mi)
        #pragma unroll
        for (int ni = 0; ni < NI; ++ni)
            acc[mi][ni] = (f32x4){0.f, 0.f, 0.f, 0.f};

    // barrier-free k-loop: A from swizzled LDS, B fragment-swizzled global
    for (int k0 = 0; k0 < K; k0 += 32) {
        short8 afh[4], afl[4];
        #pragma unroll
        for (int mi = 0; mi < 4; ++mi) {
            int r = mi * 16 + ml;
            int soff = (r * 128 + k0 + quad * 8) ^ ((r & 7) << 3);
            afh[mi] = *(const short8*)&Afh[soff];
            afl[mi] = *(const short8*)&Afl[soff];
        }
        const size_t bbase = (size_t)((k0 >> 5) * (C / 16) + wave * NI) * 512 + (size_t)lane * 8;
        #pragma unroll
        for (int ni = 0; ni < NI; ++ni) {
            short8 bh = *(const short8*)&Bhi[bbase + ni * 512];
            short8 bl = *(const short8*)&Blo[bbase + ni * 512];
            #pragma unroll
            for (int mi = 0; mi < 4; ++mi) {
                acc[mi][ni] = __builtin_amdgcn_mfma_f32_16x16x32_bf16(afl[mi], bh, acc[mi][ni], 0, 0, 0);
                acc[mi][ni] = __builtin_amdgcn_mfma_f32_16x16x32_bf16(afh[mi], bl, acc[mi][ni], 0, 0, 0);
                acc[mi][ni] = __builtin_amdgcn_mfma_f32_16x16x32_bf16(afh[mi], bh, acc[mi][ni], 0, 0, 0);
            }
        }
    }

    #pragma unroll
    for (int mi = 0; mi < 4; ++mi)
        #pragma unroll
        for (int r = 0; r < 4; ++r) {
            int node = node0 + mi * 16 + quad * 4 + r;
            if (node >= N) continue;
            #pragma unroll
            for (int ni = 0; ni < NI; ++ni) {
                int c = wave * (16 * NI) + ni * 16 + ml;
                float v = acc[mi][ni][r];
                if (c < DO) gs_out[(size_t)node * DO + c] = v;
                else        gn_out[(size_t)node * DO + (c - DO)] = bf16_rne(v);
            }
        }
}

// ---- final: out[i] = relu(gs4[nodes[i]] + mean_j gn4[nb[j]]), D_OUT=64 ----
__global__ __launch_bounds__(256)
void agg_out(const float* __restrict__ gs4, const unsigned short* __restrict__ gn4,
             const int* __restrict__ neigh, const int* __restrict__ nodes,
             float* __restrict__ out, int N)
{
    const int i    = blockIdx.x * 32 + (threadIdx.x >> 3);
    const int lane = threadIdx.x & 7;
    if (i >= N) return;
    const int nd = nodes[i];
    const int4* nb4 = (const int4*)(neigh + (size_t)nd * FANOUT);
    int4 q0 = nb4[0], q1 = nb4[1], q2 = nb4[2], q3 = nb4[3];
    int ids[FANOUT] = {q0.x, q0.y, q0.z, q0.w, q1.x, q1.y, q1.z, q1.w,
                       q2.x, q2.y, q2.z, q2.w, q3.x, q3.y, q3.z, q3.w};
    float acc[8];
    #pragma unroll
    for (int c = 0; c < 8; ++c) acc[c] = 0.f;
    #pragma unroll
    for (int j = 0; j < FANOUT; ++j) {
        uint4 q = *(const uint4*)&gn4[(size_t)ids[j] * 64 + lane * 8];
        acc[0] += __uint_as_float(q.x << 16);
        acc[1] += __uint_as_float(q.x & 0xffff0000u);
        acc[2] += __uint_as_float(q.y << 16);
        acc[3] += __uint_as_float(q.y & 0xffff0000u);
        acc[4] += __uint_as_float(q.z << 16);
        acc[5] += __uint_as_float(q.z & 0xffff0000u);
        acc[6] += __uint_as_float(q.w << 16);
        acc[7] += __uint_as_float(q.w & 0xffff0000u);
    }
    const float inv = 1.0f / (float)FANOUT;
    const float* s = gs4 + (size_t)nd * 64 + lane * 8;
    float4 s0 = *(const float4*)&s[0];
    float4 s1 = *(const float4*)&s[4];
    float4 o0, o1;
    o0.x = fmaxf(fmaf(acc[0], inv, s0.x), 0.f);
    o0.y = fmaxf(fmaf(acc[1], inv, s0.y), 0.f);
    o0.z = fmaxf(fmaf(acc[2], inv, s0.z), 0.f);
    o0.w = fmaxf(fmaf(acc[3], inv, s0.w), 0.f);
    o1.x = fmaxf(fmaf(acc[4], inv, s1.x), 0.f);
    o1.y = fmaxf(fmaf(acc[5], inv, s1.y), 0.f);
    o1.z = fmaxf(fmaf(acc[6], inv, s1.z), 0.f);
    o1.w = fmaxf(fmaf(acc[7], inv, s1.w), 0.f);
    float* op = out + (size_t)i * 64 + lane * 8;
    *(float4*)&op[0] = o0;
    *(float4*)&op[4] = o1;
}

extern "C" void kernel_launch(void* const* d_in, const int* in_sizes, int n_in,
                              void* d_out, int out_size, void* d_ws, size_t ws_size,
                              hipStream_t stream)
{
    const float* features = (const float*)d_in[0];
    const float* W1       = (const float*)d_in[1];
    const float* W2       = (const float*)d_in[2];
    const float* W3       = (const float*)d_in[3];
    const float* W4       = (const float*)d_in[4];
    const int*   nodes    = (const int*)d_in[5];
    const int*   neigh    = (const int*)d_in[6];
    float*       out      = (float*)d_out;

    unsigned short* B1h = (unsigned short*)d_ws;       // 65536
    unsigned short* B1l = B1h + 65536;
    unsigned short* B2h = B1l + 65536;                 // 32768
    unsigned short* B2l = B2h + 32768;
    unsigned short* B3h = B2l + 32768;
    unsigned short* B3l = B3h + 32768;
    unsigned short* B4h = B3l + 32768;                 // 16384
    unsigned short* B4l = B4h + 16384;
    float* gs = (float*)(B4l + 16384);                 // N*128 fp32, in-place L1-L3
    unsigned short* gnA = (unsigned short*)(gs + (size_t)N_NODES * 128); // N*128 bf16
    unsigned short* gnB = gnA + (size_t)N_NODES * 128; // N*128 bf16
    float* gs4 = (float*)gnB;                          // aliases gnB (free at L4)
    unsigned short* gn4 = gnB + (size_t)N_NODES * 128; // N*64 bf16

    prep_Bsw<<<(65536 + 255) / 256, 256, 0, stream>>>(W1, B1h, B1l, 256, 128);
    prep_Bsw<<<(32768 + 255) / 256, 256, 0, stream>>>(W2, B2h, B2l, 128, 128);
    prep_Bsw<<<(32768 + 255) / 256, 256, 0, stream>>>(W3, B3h, B3l, 128, 128);
    prep_Bsw<<<(16384 + 255) / 256, 256, 0, stream>>>(W4, B4h, B4l, 128, 64);

    const int grid = (N_NODES + 63) / 64;   // 1563

    gemm1<<<grid, 256, 0, stream>>>(features, B1h, B1l, gs, gnA, N_NODES);
    fused_layer<256><<<grid, 256, 0, stream>>>(gs, gnA, neigh, B2h, B2l, gs, gnB, N_NODES);
    fused_layer<256><<<grid, 256, 0, stream>>>(gs, gnB, neigh, B3h, B3l, gs, gnA, N_NODES);
    fused_layer<128><<<grid, 256, 0, stream>>>(gs, gnA, neigh, B4h, B4l, gs4, gn4, N_NODES);
    agg_out<<<(N_NODES + 31) / 32, 256, 0, stream>>>(gs4, gn4, neigh, nodes, out, N_NODES);
}

// Round 4
// 469.053 us; speedup vs baseline: 1.1760x; 1.1760x over previous
//
#include <hip/hip_runtime.h>
#include <hip/hip_bf16.h>

// GraphSAGE R9: R8 minus the register squeeze.
//  R8's launch_bounds(256,5) forced VGPR 64->48 -> scratch spills in the
//  A-phase (acc[32]+ids): WRITE_SIZE 75->196MB, FETCH +45MB, dur 94->148us.
//  R9: launch_bounds(256,4) (VGPR cap 128, no spills). LDS stays 32KB
//  XOR-swizzled -> HW may still fit 5 blocks/CU when VGPR<=96.
//  Keeps: quad-coalesced gather (one full 64B line per quad-instruction),
//  fragment-swizzled B in global, software-pipelined gemm1, barrier-free
//  fused k-loop.

constexpr int N_NODES = 100000;
constexpr int FANOUT  = 16;

typedef __attribute__((ext_vector_type(8))) short short8;
typedef __attribute__((ext_vector_type(4))) float f32x4;

__device__ inline unsigned short bf16_rne(float f) {
    unsigned u = __float_as_uint(f);
    return (unsigned short)((u + 0x7fffu + ((u >> 16) & 1u)) >> 16);
}
__device__ inline float bf16_tof(unsigned short s) {
    return __uint_as_float(((unsigned)s) << 16);
}

// ---- weights -> hi/lo bf16, FRAGMENT-SWIZZLED layout ----
// off(c,k) = ((tk*(C/16)+tc)*64 + qk*16 + mlc)*8 + e
//   tc=c>>4, mlc=c&15, tk=k>>5, qk=(k>>3)&3, e=k&7
__global__ __launch_bounds__(256)
void prep_Bsw(const float* __restrict__ W, unsigned short* __restrict__ Bhi,
              unsigned short* __restrict__ Blo, int D_IN, int D_OUT)
{
    int i = blockIdx.x * 256 + threadIdx.x;
    int total = 2 * D_OUT * D_IN;
    if (i >= total) return;
    int K = D_IN, C = 2 * D_OUT;
    int c = i / K, k = i % K;
    float v = (c < D_OUT) ? W[(size_t)c * (2 * K) + k]
                          : W[(size_t)(c - D_OUT) * (2 * K) + K + k];
    int tc = c >> 4, mlc = c & 15;
    int tk = k >> 5, qk = (k >> 3) & 3, e = k & 7;
    size_t off = ((size_t)(tk * (C / 16) + tc) * 64 + qk * 16 + mlc) * 8 + e;
    unsigned short hi = bf16_rne(v);
    Bhi[off] = hi;
    Blo[off] = bf16_rne(v - bf16_tof(hi));
}

// ---- gemm1: dense, K=256, C=256. block = 64 nodes, wave tile 64x64. ----
// A: software-pipelined fp32->split-bf16 LDS staging. B: swizzled global (L2).
__global__ __launch_bounds__(256, 3)
void gemm1(const float* __restrict__ hf,
           const unsigned short* __restrict__ Bhi,
           const unsigned short* __restrict__ Blo,
           float* __restrict__ gs, unsigned short* __restrict__ gn, int N)
{
    constexpr int K = 256, DO = 128, LDA = 40;
    __shared__ unsigned short Ah[64 * LDA], Al[64 * LDA];

    const int tid  = threadIdx.x;
    const int wave = tid >> 6;
    const int lane = tid & 63;
    const int ml   = lane & 15;
    const int quad = lane >> 4;
    const int node0 = blockIdx.x * 64;

    const int srow = tid >> 3;
    const int sc4  = tid & 7;
    int nd0 = node0 + srow;      if (nd0 >= N) nd0 = N - 1;
    int nd1 = node0 + srow + 32; if (nd1 >= N) nd1 = N - 1;
    const float* pA0 = &hf[(size_t)nd0 * K + sc4 * 4];
    const float* pA1 = &hf[(size_t)nd1 * K + sc4 * 4];

    f32x4 acc[4][4];
    #pragma unroll
    for (int mi = 0; mi < 4; ++mi)
        #pragma unroll
        for (int ni = 0; ni < 4; ++ni)
            acc[mi][ni] = (f32x4){0.f, 0.f, 0.f, 0.f};

    float4 pf0 = *(const float4*)&pA0[0];
    float4 pf1 = *(const float4*)&pA1[0];

    for (int k0 = 0; k0 < K; k0 += 32) {
        {
            float v0[4] = {pf0.x, pf0.y, pf0.z, pf0.w};
            float v1[4] = {pf1.x, pf1.y, pf1.z, pf1.w};
            unsigned short h0[4], l0[4], h1[4], l1[4];
            #pragma unroll
            for (int e = 0; e < 4; ++e) {
                h0[e] = bf16_rne(v0[e]); l0[e] = bf16_rne(v0[e] - bf16_tof(h0[e]));
                h1[e] = bf16_rne(v1[e]); l1[e] = bf16_rne(v1[e] - bf16_tof(h1[e]));
            }
            *(uint2*)&Ah[srow * LDA + sc4 * 4]        = *(const uint2*)h0;
            *(uint2*)&Al[srow * LDA + sc4 * 4]        = *(const uint2*)l0;
            *(uint2*)&Ah[(srow + 32) * LDA + sc4 * 4] = *(const uint2*)h1;
            *(uint2*)&Al[(srow + 32) * LDA + sc4 * 4] = *(const uint2*)l1;
        }
        if (k0 + 32 < K) {
            pf0 = *(const float4*)&pA0[k0 + 32];
            pf1 = *(const float4*)&pA1[k0 + 32];
        }
        __syncthreads();

        short8 afh[4], afl[4];
        #pragma unroll
        for (int mi = 0; mi < 4; ++mi) {
            int r = mi * 16 + ml;
            afh[mi] = *(const short8*)&Ah[r * LDA + quad * 8];
            afl[mi] = *(const short8*)&Al[r * LDA + quad * 8];
        }
        const size_t bbase = (size_t)((k0 >> 5) * 16 + wave * 4) * 512 + (size_t)lane * 8;
        #pragma unroll
        for (int ni = 0; ni < 4; ++ni) {
            short8 bh = *(const short8*)&Bhi[bbase + ni * 512];
            short8 bl = *(const short8*)&Blo[bbase + ni * 512];
            #pragma unroll
            for (int mi = 0; mi < 4; ++mi) {
                acc[mi][ni] = __builtin_amdgcn_mfma_f32_16x16x32_bf16(afl[mi], bh, acc[mi][ni], 0, 0, 0);
                acc[mi][ni] = __builtin_amdgcn_mfma_f32_16x16x32_bf16(afh[mi], bl, acc[mi][ni], 0, 0, 0);
                acc[mi][ni] = __builtin_amdgcn_mfma_f32_16x16x32_bf16(afh[mi], bh, acc[mi][ni], 0, 0, 0);
            }
        }
        __syncthreads();
    }

    #pragma unroll
    for (int mi = 0; mi < 4; ++mi)
        #pragma unroll
        for (int r = 0; r < 4; ++r) {
            int node = node0 + mi * 16 + quad * 4 + r;
            if (node >= N) continue;
            #pragma unroll
            for (int ni = 0; ni < 4; ++ni) {
                int c = wave * 64 + ni * 16 + ml;
                float v = acc[mi][ni][r];
                if (c < DO) gs[(size_t)node * DO + c] = v;
                else        gn[(size_t)node * DO + (c - DO)] = bf16_rne(v);
            }
        }
}

// ---- fused layer: quad-coalesced gather + XOR-swizzled A-LDS + MFMA ----
// D_IN=128 fixed. C=256 (DO=128) or C=128 (DO=64).
template<int C>
__global__ __launch_bounds__(256, 4)
void fused_layer(const float* __restrict__ gs_in,
                 const unsigned short* __restrict__ gn_in,
                 const int* __restrict__ neigh,
                 const unsigned short* __restrict__ Bhi,
                 const unsigned short* __restrict__ Blo,
                 float* __restrict__ gs_out,
                 unsigned short* __restrict__ gn_out, int N)
{
    constexpr int K = 128, DO = C / 2, NI = C / 64;
    __shared__ unsigned short Afh[64 * 128], Afl[64 * 128];   // 32768 B total

    const int tid  = threadIdx.x;
    const int wave = tid >> 6;
    const int lane = tid & 63;
    const int ml   = lane & 15;
    const int quad = lane >> 4;
    const int node0 = blockIdx.x * 64;

    // ---- A-phase: h = relu(gs + mean*gn[nb]); lane (row,seg) owns col
    // chunks [32t+8seg, +8) t=0..3 -> quad instruction = one full 64B line.
    {
        const int row = tid >> 2;
        const int seg = tid & 3;
        int nd = node0 + row; if (nd >= N) nd = N - 1;
        const int4* nb4 = (const int4*)(neigh + (size_t)nd * FANOUT);
        int4 q0 = nb4[0], q1 = nb4[1], q2 = nb4[2], q3 = nb4[3];
        int ids[FANOUT] = {q0.x, q0.y, q0.z, q0.w, q1.x, q1.y, q1.z, q1.w,
                           q2.x, q2.y, q2.z, q2.w, q3.x, q3.y, q3.z, q3.w};
        float acc[32];
        #pragma unroll
        for (int c = 0; c < 32; ++c) acc[c] = 0.f;
        #pragma unroll
        for (int j = 0; j < FANOUT; ++j) {
            const uint4* src = (const uint4*)&gn_in[(size_t)ids[j] * 128];
            #pragma unroll
            for (int t = 0; t < 4; ++t) {
                uint4 q = src[4 * t + seg];
                acc[t*8+0] += __uint_as_float(q.x << 16);
                acc[t*8+1] += __uint_as_float(q.x & 0xffff0000u);
                acc[t*8+2] += __uint_as_float(q.y << 16);
                acc[t*8+3] += __uint_as_float(q.y & 0xffff0000u);
                acc[t*8+4] += __uint_as_float(q.z << 16);
                acc[t*8+5] += __uint_as_float(q.z & 0xffff0000u);
                acc[t*8+6] += __uint_as_float(q.w << 16);
                acc[t*8+7] += __uint_as_float(q.w & 0xffff0000u);
            }
        }
        const float inv = 1.0f / (float)FANOUT;
        const float* gsp = &gs_in[(size_t)nd * 128];
        #pragma unroll
        for (int t = 0; t < 4; ++t) {
            float4 s0 = *(const float4*)&gsp[32 * t + 8 * seg];
            float4 s1 = *(const float4*)&gsp[32 * t + 8 * seg + 4];
            float sv[8] = {s0.x, s0.y, s0.z, s0.w, s1.x, s1.y, s1.z, s1.w};
            alignas(16) unsigned short th[8], tl[8];
            #pragma unroll
            for (int e = 0; e < 8; ++e) {
                float h = fmaxf(fmaf(acc[t*8+e], inv, sv[e]), 0.f);
                unsigned short hi = bf16_rne(h);
                th[e] = hi;
                tl[e] = bf16_rne(h - bf16_tof(hi));
            }
            int soff = (row * 128 + 32 * t + 8 * seg) ^ ((row & 7) << 3);
            *(uint4*)&Afh[soff] = *(const uint4*)th;
            *(uint4*)&Afl[soff] = *(const uint4*)tl;
        }
    }
    __syncthreads();

    f32x4 acc[4][NI];
    #pragma unroll
    for (int mi = 0; mi < 4; ++mi)
        #pragma unroll
        for (int ni = 0; ni < NI; ++ni)
            acc[mi][ni] = (f32x4){0.f, 0.f, 0.f, 0.f};

    // barrier-free k-loop: A from swizzled LDS, B fragment-swizzled global
    for (int k0 = 0; k0 < K; k0 += 32) {
        short8 afh[4], afl[4];
        #pragma unroll
        for (int mi = 0; mi < 4; ++mi) {
            int r = mi * 16 + ml;
            int soff = (r * 128 + k0 + quad * 8) ^ ((r & 7) << 3);
            afh[mi] = *(const short8*)&Afh[soff];
            afl[mi] = *(const short8*)&Afl[soff];
        }
        const size_t bbase = (size_t)((k0 >> 5) * (C / 16) + wave * NI) * 512 + (size_t)lane * 8;
        #pragma unroll
        for (int ni = 0; ni < NI; ++ni) {
            short8 bh = *(const short8*)&Bhi[bbase + ni * 512];
            short8 bl = *(const short8*)&Blo[bbase + ni * 512];
            #pragma unroll
            for (int mi = 0; mi < 4; ++mi) {
                acc[mi][ni] = __builtin_amdgcn_mfma_f32_16x16x32_bf16(afl[mi], bh, acc[mi][ni], 0, 0, 0);
                acc[mi][ni] = __builtin_amdgcn_mfma_f32_16x16x32_bf16(afh[mi], bl, acc[mi][ni], 0, 0, 0);
                acc[mi][ni] = __builtin_amdgcn_mfma_f32_16x16x32_bf16(afh[mi], bh, acc[mi][ni], 0, 0, 0);
            }
        }
    }

    #pragma unroll
    for (int mi = 0; mi < 4; ++mi)
        #pragma unroll
        for (int r = 0; r < 4; ++r) {
            int node = node0 + mi * 16 + quad * 4 + r;
            if (node >= N) continue;
            #pragma unroll
            for (int ni = 0; ni < NI; ++ni) {
                int c = wave * (16 * NI) + ni * 16 + ml;
                float v = acc[mi][ni][r];
                if (c < DO) gs_out[(size_t)node * DO + c] = v;
                else        gn_out[(size_t)node * DO + (c - DO)] = bf16_rne(v);
            }
        }
}

// ---- final: out[i] = relu(gs4[nodes[i]] + mean_j gn4[nb[j]]), D_OUT=64 ----
__global__ __launch_bounds__(256)
void agg_out(const float* __restrict__ gs4, const unsigned short* __restrict__ gn4,
             const int* __restrict__ neigh, const int* __restrict__ nodes,
             float* __restrict__ out, int N)
{
    const int i    = blockIdx.x * 32 + (threadIdx.x >> 3);
    const int lane = threadIdx.x & 7;
    if (i >= N) return;
    const int nd = nodes[i];
    const int4* nb4 = (const int4*)(neigh + (size_t)nd * FANOUT);
    int4 q0 = nb4[0], q1 = nb4[1], q2 = nb4[2], q3 = nb4[3];
    int ids[FANOUT] = {q0.x, q0.y, q0.z, q0.w, q1.x, q1.y, q1.z, q1.w,
                       q2.x, q2.y, q2.z, q2.w, q3.x, q3.y, q3.z, q3.w};
    float acc[8];
    #pragma unroll
    for (int c = 0; c < 8; ++c) acc[c] = 0.f;
    #pragma unroll
    for (int j = 0; j < FANOUT; ++j) {
        uint4 q = *(const uint4*)&gn4[(size_t)ids[j] * 64 + lane * 8];
        acc[0] += __uint_as_float(q.x << 16);
        acc[1] += __uint_as_float(q.x & 0xffff0000u);
        acc[2] += __uint_as_float(q.y << 16);
        acc[3] += __uint_as_float(q.y & 0xffff0000u);
        acc[4] += __uint_as_float(q.z << 16);
        acc[5] += __uint_as_float(q.z & 0xffff0000u);
        acc[6] += __uint_as_float(q.w << 16);
        acc[7] += __uint_as_float(q.w & 0xffff0000u);
    }
    const float inv = 1.0f / (float)FANOUT;
    const float* s = gs4 + (size_t)nd * 64 + lane * 8;
    float4 s0 = *(const float4*)&s[0];
    float4 s1 = *(const float4*)&s[4];
    float4 o0, o1;
    o0.x = fmaxf(fmaf(acc[0], inv, s0.x), 0.f);
    o0.y = fmaxf(fmaf(acc[1], inv, s0.y), 0.f);
    o0.z = fmaxf(fmaf(acc[2], inv, s0.z), 0.f);
    o0.w = fmaxf(fmaf(acc[3], inv, s0.w), 0.f);
    o1.x = fmaxf(fmaf(acc[4], inv, s1.x), 0.f);
    o1.y = fmaxf(fmaf(acc[5], inv, s1.y), 0.f);
    o1.z = fmaxf(fmaf(acc[6], inv, s1.z), 0.f);
    o1.w = fmaxf(fmaf(acc[7], inv, s1.w), 0.f);
    float* op = out + (size_t)i * 64 + lane * 8;
    *(float4*)&op[0] = o0;
    *(float4*)&op[4] = o1;
}

extern "C" void kernel_launch(void* const* d_in, const int* in_sizes, int n_in,
                              void* d_out, int out_size, void* d_ws, size_t ws_size,
                              hipStream_t stream)
{
    const float* features = (const float*)d_in[0];
    const float* W1       = (const float*)d_in[1];
    const float* W2       = (const float*)d_in[2];
    const float* W3       = (const float*)d_in[3];
    const float* W4       = (const float*)d_in[4];
    const int*   nodes    = (const int*)d_in[5];
    const int*   neigh    = (const int*)d_in[6];
    float*       out      = (float*)d_out;

    unsigned short* B1h = (unsigned short*)d_ws;       // 65536
    unsigned short* B1l = B1h + 65536;
    unsigned short* B2h = B1l + 65536;                 // 32768
    unsigned short* B2l = B2h + 32768;
    unsigned short* B3h = B2l + 32768;
    unsigned short* B3l = B3h + 32768;
    unsigned short* B4h = B3l + 32768;                 // 16384
    unsigned short* B4l = B4h + 16384;
    float* gs = (float*)(B4l + 16384);                 // N*128 fp32, in-place L1-L3
    unsigned short* gnA = (unsigned short*)(gs + (size_t)N_NODES * 128); // N*128 bf16
    unsigned short* gnB = gnA + (size_t)N_NODES * 128; // N*128 bf16
    float* gs4 = (float*)gnB;                          // aliases gnB (free at L4)
    unsigned short* gn4 = gnB + (size_t)N_NODES * 128; // N*64 bf16

    prep_Bsw<<<(65536 + 255) / 256, 256, 0, stream>>>(W1, B1h, B1l, 256, 128);
    prep_Bsw<<<(32768 + 255) / 256, 256, 0, stream>>>(W2, B2h, B2l, 128, 128);
    prep_Bsw<<<(32768 + 255) / 256, 256, 0, stream>>>(W3, B3h, B3l, 128, 128);
    prep_Bsw<<<(16384 + 255) / 256, 256, 0, stream>>>(W4, B4h, B4l, 128, 64);

    const int grid = (N_NODES + 63) / 64;   // 1563

    gemm1<<<grid, 256, 0, stream>>>(features, B1h, B1l, gs, gnA, N_NODES);
    fused_layer<256><<<grid, 256, 0, stream>>>(gs, gnA, neigh, B2h, B2l, gs, gnB, N_NODES);
    fused_layer<256><<<grid, 256, 0, stream>>>(gs, gnB, neigh, B3h, B3l, gs, gnA, N_NODES);
    fused_layer<128><<<grid, 256, 0, stream>>>(gs, gnA, neigh, B4h, B4l, gs4, gn4, N_NODES);
    agg_out<<<(N_NODES + 31) / 32, 256, 0, stream>>>(gs4, gn4, neigh, nodes, out, N_NODES);
}

// Round 5
// 456.556 us; speedup vs baseline: 1.2082x; 1.0274x over previous
//
#include <hip/hip_runtime.h>
#include <hip/hip_bf16.h>

// GraphSAGE R10: fused_layer re-tiled 64->32 nodes/block to break the
// register-file occupancy ceiling. gfx950 unified RF = 512 regs/lane:
// old tile (acc[4][4]=64 AGPR + 64 VGPR = 128) -> 4 waves/SIMD. New tile:
// acc[2][NI]=32 AGPR + ~50 VGPR -> 6-7 waves/SIMD; LDS 16KB (7 blocks fit).
// Gather: 8 threads/row, chunks c0=64(s>>2)+8(s&3), c1=c0+32 so each quad
// load = one full 64B line (keeps R9 coalescing). launch_bounds(256,6)
// caps regs at 85 (est. 72; spill falsifier = WRITE_SIZE >> 75MB).
// gemm1/agg_out unchanged (single-variable experiment).

constexpr int N_NODES = 100000;
constexpr int FANOUT  = 16;

typedef __attribute__((ext_vector_type(8))) short short8;
typedef __attribute__((ext_vector_type(4))) float f32x4;

__device__ inline unsigned short bf16_rne(float f) {
    unsigned u = __float_as_uint(f);
    return (unsigned short)((u + 0x7fffu + ((u >> 16) & 1u)) >> 16);
}
__device__ inline float bf16_tof(unsigned short s) {
    return __uint_as_float(((unsigned)s) << 16);
}

// ---- weights -> hi/lo bf16, FRAGMENT-SWIZZLED layout ----
// off(c,k) = ((tk*(C/16)+tc)*64 + qk*16 + mlc)*8 + e
//   tc=c>>4, mlc=c&15, tk=k>>5, qk=(k>>3)&3, e=k&7
__global__ __launch_bounds__(256)
void prep_Bsw(const float* __restrict__ W, unsigned short* __restrict__ Bhi,
              unsigned short* __restrict__ Blo, int D_IN, int D_OUT)
{
    int i = blockIdx.x * 256 + threadIdx.x;
    int total = 2 * D_OUT * D_IN;
    if (i >= total) return;
    int K = D_IN, C = 2 * D_OUT;
    int c = i / K, k = i % K;
    float v = (c < D_OUT) ? W[(size_t)c * (2 * K) + k]
                          : W[(size_t)(c - D_OUT) * (2 * K) + K + k];
    int tc = c >> 4, mlc = c & 15;
    int tk = k >> 5, qk = (k >> 3) & 3, e = k & 7;
    size_t off = ((size_t)(tk * (C / 16) + tc) * 64 + qk * 16 + mlc) * 8 + e;
    unsigned short hi = bf16_rne(v);
    Bhi[off] = hi;
    Blo[off] = bf16_rne(v - bf16_tof(hi));
}

// ---- gemm1: dense, K=256, C=256. block = 64 nodes, wave tile 64x64. ----
// (unchanged from R9: pipelined A staging, fragment-swizzled B from L2)
__global__ __launch_bounds__(256, 3)
void gemm1(const float* __restrict__ hf,
           const unsigned short* __restrict__ Bhi,
           const unsigned short* __restrict__ Blo,
           float* __restrict__ gs, unsigned short* __restrict__ gn, int N)
{
    constexpr int K = 256, DO = 128, LDA = 40;
    __shared__ unsigned short Ah[64 * LDA], Al[64 * LDA];

    const int tid  = threadIdx.x;
    const int wave = tid >> 6;
    const int lane = tid & 63;
    const int ml   = lane & 15;
    const int quad = lane >> 4;
    const int node0 = blockIdx.x * 64;

    const int srow = tid >> 3;
    const int sc4  = tid & 7;
    int nd0 = node0 + srow;      if (nd0 >= N) nd0 = N - 1;
    int nd1 = node0 + srow + 32; if (nd1 >= N) nd1 = N - 1;
    const float* pA0 = &hf[(size_t)nd0 * K + sc4 * 4];
    const float* pA1 = &hf[(size_t)nd1 * K + sc4 * 4];

    f32x4 acc[4][4];
    #pragma unroll
    for (int mi = 0; mi < 4; ++mi)
        #pragma unroll
        for (int ni = 0; ni < 4; ++ni)
            acc[mi][ni] = (f32x4){0.f, 0.f, 0.f, 0.f};

    float4 pf0 = *(const float4*)&pA0[0];
    float4 pf1 = *(const float4*)&pA1[0];

    for (int k0 = 0; k0 < K; k0 += 32) {
        {
            float v0[4] = {pf0.x, pf0.y, pf0.z, pf0.w};
            float v1[4] = {pf1.x, pf1.y, pf1.z, pf1.w};
            unsigned short h0[4], l0[4], h1[4], l1[4];
            #pragma unroll
            for (int e = 0; e < 4; ++e) {
                h0[e] = bf16_rne(v0[e]); l0[e] = bf16_rne(v0[e] - bf16_tof(h0[e]));
                h1[e] = bf16_rne(v1[e]); l1[e] = bf16_rne(v1[e] - bf16_tof(h1[e]));
            }
            *(uint2*)&Ah[srow * LDA + sc4 * 4]        = *(const uint2*)h0;
            *(uint2*)&Al[srow * LDA + sc4 * 4]        = *(const uint2*)l0;
            *(uint2*)&Ah[(srow + 32) * LDA + sc4 * 4] = *(const uint2*)h1;
            *(uint2*)&Al[(srow + 32) * LDA + sc4 * 4] = *(const uint2*)l1;
        }
        if (k0 + 32 < K) {
            pf0 = *(const float4*)&pA0[k0 + 32];
            pf1 = *(const float4*)&pA1[k0 + 32];
        }
        __syncthreads();

        short8 afh[4], afl[4];
        #pragma unroll
        for (int mi = 0; mi < 4; ++mi) {
            int r = mi * 16 + ml;
            afh[mi] = *(const short8*)&Ah[r * LDA + quad * 8];
            afl[mi] = *(const short8*)&Al[r * LDA + quad * 8];
        }
        const size_t bbase = (size_t)((k0 >> 5) * 16 + wave * 4) * 512 + (size_t)lane * 8;
        #pragma unroll
        for (int ni = 0; ni < 4; ++ni) {
            short8 bh = *(const short8*)&Bhi[bbase + ni * 512];
            short8 bl = *(const short8*)&Blo[bbase + ni * 512];
            #pragma unroll
            for (int mi = 0; mi < 4; ++mi) {
                acc[mi][ni] = __builtin_amdgcn_mfma_f32_16x16x32_bf16(afl[mi], bh, acc[mi][ni], 0, 0, 0);
                acc[mi][ni] = __builtin_amdgcn_mfma_f32_16x16x32_bf16(afh[mi], bl, acc[mi][ni], 0, 0, 0);
                acc[mi][ni] = __builtin_amdgcn_mfma_f32_16x16x32_bf16(afh[mi], bh, acc[mi][ni], 0, 0, 0);
            }
        }
        __syncthreads();
    }

    #pragma unroll
    for (int mi = 0; mi < 4; ++mi)
        #pragma unroll
        for (int r = 0; r < 4; ++r) {
            int node = node0 + mi * 16 + quad * 4 + r;
            if (node >= N) continue;
            #pragma unroll
            for (int ni = 0; ni < 4; ++ni) {
                int c = wave * 64 + ni * 16 + ml;
                float v = acc[mi][ni][r];
                if (c < DO) gs[(size_t)node * DO + c] = v;
                else        gn[(size_t)node * DO + (c - DO)] = bf16_rne(v);
            }
        }
}

// ---- fused layer: 32 nodes/block, high-occupancy tile ----
// D_IN=128 fixed. C=256 (DO=128, NI=4) or C=128 (DO=64, NI=2).
template<int C>
__global__ __launch_bounds__(256, 6)
void fused_layer(const float* __restrict__ gs_in,
                 const unsigned short* __restrict__ gn_in,
                 const int* __restrict__ neigh,
                 const unsigned short* __restrict__ Bhi,
                 const unsigned short* __restrict__ Blo,
                 float* __restrict__ gs_out,
                 unsigned short* __restrict__ gn_out, int N)
{
    constexpr int K = 128, DO = C / 2, NI = C / 64;
    __shared__ unsigned short Afh[32 * 128], Afl[32 * 128];   // 16384 B total

    const int tid  = threadIdx.x;
    const int wave = tid >> 6;
    const int lane = tid & 63;
    const int ml   = lane & 15;
    const int quad = lane >> 4;
    const int node0 = blockIdx.x * 32;

    // ---- A-phase: h = relu(gs + mean*gn[nb]); 8 threads/row, thread s
    // owns chunks c0=64(s>>2)+8(s&3) and c1=c0+32 -> each quad load
    // instruction covers one full 64B line of the neighbor row.
    {
        const int row = tid >> 3;          // node within block (0..31)
        const int s   = tid & 7;
        const int c0  = 64 * (s >> 2) + 8 * (s & 3);
        const int c1  = c0 + 32;
        int nd = node0 + row; if (nd >= N) nd = N - 1;
        const int4* nb4 = (const int4*)(neigh + (size_t)nd * FANOUT);
        int4 q0 = nb4[0], q1 = nb4[1], q2 = nb4[2], q3 = nb4[3];
        int ids[FANOUT] = {q0.x, q0.y, q0.z, q0.w, q1.x, q1.y, q1.z, q1.w,
                           q2.x, q2.y, q2.z, q2.w, q3.x, q3.y, q3.z, q3.w};
        float acc[16];
        #pragma unroll
        for (int c = 0; c < 16; ++c) acc[c] = 0.f;
        #pragma unroll
        for (int j = 0; j < FANOUT; ++j) {
            const uint4* src = (const uint4*)&gn_in[(size_t)ids[j] * 128];
            uint4 qa = src[c0 >> 3];
            uint4 qb = src[c1 >> 3];
            acc[0]  += __uint_as_float(qa.x << 16);
            acc[1]  += __uint_as_float(qa.x & 0xffff0000u);
            acc[2]  += __uint_as_float(qa.y << 16);
            acc[3]  += __uint_as_float(qa.y & 0xffff0000u);
            acc[4]  += __uint_as_float(qa.z << 16);
            acc[5]  += __uint_as_float(qa.z & 0xffff0000u);
            acc[6]  += __uint_as_float(qa.w << 16);
            acc[7]  += __uint_as_float(qa.w & 0xffff0000u);
            acc[8]  += __uint_as_float(qb.x << 16);
            acc[9]  += __uint_as_float(qb.x & 0xffff0000u);
            acc[10] += __uint_as_float(qb.y << 16);
            acc[11] += __uint_as_float(qb.y & 0xffff0000u);
            acc[12] += __uint_as_float(qb.z << 16);
            acc[13] += __uint_as_float(qb.z & 0xffff0000u);
            acc[14] += __uint_as_float(qb.w << 16);
            acc[15] += __uint_as_float(qb.w & 0xffff0000u);
        }
        const float inv = 1.0f / (float)FANOUT;
        const float* gsp = &gs_in[(size_t)nd * 128];
        #pragma unroll
        for (int cc = 0; cc < 2; ++cc) {
            const int ch = cc ? c1 : c0;
            float4 g0 = *(const float4*)&gsp[ch];
            float4 g1 = *(const float4*)&gsp[ch + 4];
            float sv[8] = {g0.x, g0.y, g0.z, g0.w, g1.x, g1.y, g1.z, g1.w};
            alignas(16) unsigned short th[8], tl[8];
            #pragma unroll
            for (int e = 0; e < 8; ++e) {
                float h = fmaxf(fmaf(acc[cc * 8 + e], inv, sv[e]), 0.f);
                unsigned short hi = bf16_rne(h);
                th[e] = hi;
                tl[e] = bf16_rne(h - bf16_tof(hi));
            }
            int soff = (row * 128 + ch) ^ ((row & 7) << 3);
            *(uint4*)&Afh[soff] = *(const uint4*)th;
            *(uint4*)&Afl[soff] = *(const uint4*)tl;
        }
    }
    __syncthreads();

    f32x4 acc[2][NI];
    #pragma unroll
    for (int mi = 0; mi < 2; ++mi)
        #pragma unroll
        for (int ni = 0; ni < NI; ++ni)
            acc[mi][ni] = (f32x4){0.f, 0.f, 0.f, 0.f};

    // barrier-free k-loop: A from swizzled LDS, B fragment-swizzled global
    for (int k0 = 0; k0 < K; k0 += 32) {
        short8 afh[2], afl[2];
        #pragma unroll
        for (int mi = 0; mi < 2; ++mi) {
            int r = mi * 16 + ml;
            int soff = (r * 128 + k0 + quad * 8) ^ ((r & 7) << 3);
            afh[mi] = *(const short8*)&Afh[soff];
            afl[mi] = *(const short8*)&Afl[soff];
        }
        const size_t bbase = (size_t)((k0 >> 5) * (C / 16) + wave * NI) * 512 + (size_t)lane * 8;
        #pragma unroll
        for (int ni = 0; ni < NI; ++ni) {
            short8 bh = *(const short8*)&Bhi[bbase + ni * 512];
            short8 bl = *(const short8*)&Blo[bbase + ni * 512];
            #pragma unroll
            for (int mi = 0; mi < 2; ++mi) {
                acc[mi][ni] = __builtin_amdgcn_mfma_f32_16x16x32_bf16(afl[mi], bh, acc[mi][ni], 0, 0, 0);
                acc[mi][ni] = __builtin_amdgcn_mfma_f32_16x16x32_bf16(afh[mi], bl, acc[mi][ni], 0, 0, 0);
                acc[mi][ni] = __builtin_amdgcn_mfma_f32_16x16x32_bf16(afh[mi], bh, acc[mi][ni], 0, 0, 0);
            }
        }
    }

    #pragma unroll
    for (int mi = 0; mi < 2; ++mi)
        #pragma unroll
        for (int r = 0; r < 4; ++r) {
            int node = node0 + mi * 16 + quad * 4 + r;
            if (node >= N) continue;
            #pragma unroll
            for (int ni = 0; ni < NI; ++ni) {
                int c = wave * (16 * NI) + ni * 16 + ml;
                float v = acc[mi][ni][r];
                if (c < DO) gs_out[(size_t)node * DO + c] = v;
                else        gn_out[(size_t)node * DO + (c - DO)] = bf16_rne(v);
            }
        }
}

// ---- final: out[i] = relu(gs4[nodes[i]] + mean_j gn4[nb[j]]), D_OUT=64 ----
__global__ __launch_bounds__(256)
void agg_out(const float* __restrict__ gs4, const unsigned short* __restrict__ gn4,
             const int* __restrict__ neigh, const int* __restrict__ nodes,
             float* __restrict__ out, int N)
{
    const int i    = blockIdx.x * 32 + (threadIdx.x >> 3);
    const int lane = threadIdx.x & 7;
    if (i >= N) return;
    const int nd = nodes[i];
    const int4* nb4 = (const int4*)(neigh + (size_t)nd * FANOUT);
    int4 q0 = nb4[0], q1 = nb4[1], q2 = nb4[2], q3 = nb4[3];
    int ids[FANOUT] = {q0.x, q0.y, q0.z, q0.w, q1.x, q1.y, q1.z, q1.w,
                       q2.x, q2.y, q2.z, q2.w, q3.x, q3.y, q3.z, q3.w};
    float acc[8];
    #pragma unroll
    for (int c = 0; c < 8; ++c) acc[c] = 0.f;
    #pragma unroll
    for (int j = 0; j < FANOUT; ++j) {
        uint4 q = *(const uint4*)&gn4[(size_t)ids[j] * 64 + lane * 8];
        acc[0] += __uint_as_float(q.x << 16);
        acc[1] += __uint_as_float(q.x & 0xffff0000u);
        acc[2] += __uint_as_float(q.y << 16);
        acc[3] += __uint_as_float(q.y & 0xffff0000u);
        acc[4] += __uint_as_float(q.z << 16);
        acc[5] += __uint_as_float(q.z & 0xffff0000u);
        acc[6] += __uint_as_float(q.w << 16);
        acc[7] += __uint_as_float(q.w & 0xffff0000u);
    }
    const float inv = 1.0f / (float)FANOUT;
    const float* s = gs4 + (size_t)nd * 64 + lane * 8;
    float4 s0 = *(const float4*)&s[0];
    float4 s1 = *(const float4*)&s[4];
    float4 o0, o1;
    o0.x = fmaxf(fmaf(acc[0], inv, s0.x), 0.f);
    o0.y = fmaxf(fmaf(acc[1], inv, s0.y), 0.f);
    o0.z = fmaxf(fmaf(acc[2], inv, s0.z), 0.f);
    o0.w = fmaxf(fmaf(acc[3], inv, s0.w), 0.f);
    o1.x = fmaxf(fmaf(acc[4], inv, s1.x), 0.f);
    o1.y = fmaxf(fmaf(acc[5], inv, s1.y), 0.f);
    o1.z = fmaxf(fmaf(acc[6], inv, s1.z), 0.f);
    o1.w = fmaxf(fmaf(acc[7], inv, s1.w), 0.f);
    float* op = out + (size_t)i * 64 + lane * 8;
    *(float4*)&op[0] = o0;
    *(float4*)&op[4] = o1;
}

extern "C" void kernel_launch(void* const* d_in, const int* in_sizes, int n_in,
                              void* d_out, int out_size, void* d_ws, size_t ws_size,
                              hipStream_t stream)
{
    const float* features = (const float*)d_in[0];
    const float* W1       = (const float*)d_in[1];
    const float* W2       = (const float*)d_in[2];
    const float* W3       = (const float*)d_in[3];
    const float* W4       = (const float*)d_in[4];
    const int*   nodes    = (const int*)d_in[5];
    const int*   neigh    = (const int*)d_in[6];
    float*       out      = (float*)d_out;

    unsigned short* B1h = (unsigned short*)d_ws;       // 65536
    unsigned short* B1l = B1h + 65536;
    unsigned short* B2h = B1l + 65536;                 // 32768
    unsigned short* B2l = B2h + 32768;
    unsigned short* B3h = B2l + 32768;
    unsigned short* B3l = B3h + 32768;
    unsigned short* B4h = B3l + 32768;                 // 16384
    unsigned short* B4l = B4h + 16384;
    float* gs = (float*)(B4l + 16384);                 // N*128 fp32, in-place L1-L3
    unsigned short* gnA = (unsigned short*)(gs + (size_t)N_NODES * 128); // N*128 bf16
    unsigned short* gnB = gnA + (size_t)N_NODES * 128; // N*128 bf16
    float* gs4 = (float*)gnB;                          // aliases gnB (free at L4)
    unsigned short* gn4 = gnB + (size_t)N_NODES * 128; // N*64 bf16

    prep_Bsw<<<(65536 + 255) / 256, 256, 0, stream>>>(W1, B1h, B1l, 256, 128);
    prep_Bsw<<<(32768 + 255) / 256, 256, 0, stream>>>(W2, B2h, B2l, 128, 128);
    prep_Bsw<<<(32768 + 255) / 256, 256, 0, stream>>>(W3, B3h, B3l, 128, 128);
    prep_Bsw<<<(16384 + 255) / 256, 256, 0, stream>>>(W4, B4h, B4l, 128, 64);

    const int grid64 = (N_NODES + 63) / 64;   // 1563
    const int grid32 = (N_NODES + 31) / 32;   // 3125

    gemm1<<<grid64, 256, 0, stream>>>(features, B1h, B1l, gs, gnA, N_NODES);
    fused_layer<256><<<grid32, 256, 0, stream>>>(gs, gnA, neigh, B2h, B2l, gs, gnB, N_NODES);
    fused_layer<256><<<grid32, 256, 0, stream>>>(gs, gnB, neigh, B3h, B3l, gs, gnA, N_NODES);
    fused_layer<128><<<grid32, 256, 0, stream>>>(gs, gnA, neigh, B4h, B4l, gs4, gn4, N_NODES);
    agg_out<<<(N_NODES + 31) / 32, 256, 0, stream>>>(gs4, gn4, neigh, nodes, out, N_NODES);
}